// Round 3
// baseline (5791.146 us; speedup 1.0000x reference)
//
#include <hip/hip_runtime.h>
#include <hip/hip_bf16.h>

// ---------------------------------------------------------------------------
// GNNProcessor: 2-block GNN, H=128. bf16 MFMA (16x16x32) with f32 accum.
// Structure per MLP kernel: 64 rows/block, 256 thr (4 waves), each wave owns
// 2 N-tiles (32 cols), 4 M-tiles; activations in LDS with padded strides.
// Weights pre-packed to B-fragment order (lane-contiguous 16B loads).
// segment_sum fused as f32 atomicAdd in the edge-MLP epilogue.
// ---------------------------------------------------------------------------

#define NN 25000
#define NE 400000
#define HDIM 128

typedef __bf16 bf16_t;
typedef __attribute__((ext_vector_type(8))) __bf16 v8bf;
typedef __attribute__((ext_vector_type(4))) __bf16 v4bf;
typedef __attribute__((ext_vector_type(4))) float f32x4;
typedef __attribute__((ext_vector_type(4))) unsigned int u32x4;

// ---- workspace layout (bytes). total = 135,448,576 ----
#define WS_PW   0            // packed bf16 weights (331776 elems = 663552 B)
#define WS_XB   1048576      // x bf16        [25000*128]  (6.4 MB)
#define WS_XC   7448576      // x f32 master  [25000*128]  (12.8 MB)
#define WS_AGG  20248576     // agg f32       [25000*128]  (12.8 MB)
#define WS_EB   33048576     // e bf16        [400000*128] (102.4 MB)

// packed-weight element offsets (order matches PackArgs below)
#define PW_EMB1   0
#define PW_EMB2   4096
#define PW_EMB3   20480
#define PW_EDGE1  36864      // + l*81920 ; W2=+49152 ; W3=+65536
#define PW_NODE1  200704     // + l*65536 ; W2=+32768 ; W3=+49152
#define PW_TOTAL  331776

__device__ __forceinline__ float silu_f(float x) { return x / (1.f + __expf(-x)); }

__device__ __forceinline__ void zacc(f32x4 (&acc)[4][2]) {
#pragma unroll
  for (int m = 0; m < 4; ++m)
#pragma unroll
    for (int n = 0; n < 2; ++n) {
      acc[m][n][0] = 0.f; acc[m][n][1] = 0.f; acc[m][n][2] = 0.f; acc[m][n][3] = 0.f;
    }
}

// A: LDS tile [64 rows][K], row stride SA bytes (multiple of 16, odd*16 -> no conflicts)
// pw: packed B frags: elem ((kt*8 + ntG)*64 + lane)*8 + j == W[kt*32+(l>>4)*8+j][ntG*16+(l&15)]
template<int KT, int SA>
__device__ __forceinline__ void mfma_gemm(const char* A, const bf16_t* __restrict__ pw,
                                          f32x4 (&acc)[4][2], int lane, int wave) {
  const int lrow  = lane & 15;
  const int lkoff = (lane >> 4) * 16;  // byte offset inside a 32-col (64B) k-tile
#pragma unroll
  for (int kt = 0; kt < KT; ++kt) {
    const v8bf b0 = *reinterpret_cast<const v8bf*>(pw + ((kt * 8 + wave * 2 + 0) * 64 + lane) * 8);
    const v8bf b1 = *reinterpret_cast<const v8bf*>(pw + ((kt * 8 + wave * 2 + 1) * 64 + lane) * 8);
#pragma unroll
    for (int mt = 0; mt < 4; ++mt) {
      const v8bf a = *reinterpret_cast<const v8bf*>(A + (mt * 16 + lrow) * SA + kt * 64 + lkoff);
      acc[mt][0] = __builtin_amdgcn_mfma_f32_16x16x32_bf16(a, b0, acc[mt][0], 0, 0, 0);
      acc[mt][1] = __builtin_amdgcn_mfma_f32_16x16x32_bf16(a, b1, acc[mt][1], 0, 0, 0);
    }
  }
}

// store acc -> bf16 hidden tile [64][128], row stride 272B, with bias (+SiLU)
__device__ __forceinline__ void store_h_bf16(char* H, const f32x4 (&acc)[4][2],
                                             const float* __restrict__ bias,
                                             int lane, int wave, bool dosilu) {
  const int lcol = lane & 15, lr4 = (lane >> 4) * 4;
#pragma unroll
  for (int n = 0; n < 2; ++n) {
    const int col = (wave * 2 + n) * 16 + lcol;
    const float b = bias[col];
#pragma unroll
    for (int mt = 0; mt < 4; ++mt)
#pragma unroll
      for (int rr = 0; rr < 4; ++rr) {
        const int row = mt * 16 + lr4 + rr;
        float v = acc[mt][n][rr] + b;
        if (dosilu) v = silu_f(v);
        *reinterpret_cast<bf16_t*>(H + row * 272 + col * 2) = (bf16_t)v;
      }
  }
}

// store acc -> f32 tile [64][128], row stride 528B, with bias (pre-LayerNorm h)
__device__ __forceinline__ void store_h_f32(char* H, const f32x4 (&acc)[4][2],
                                            const float* __restrict__ bias,
                                            int lane, int wave) {
  const int lcol = lane & 15, lr4 = (lane >> 4) * 4;
#pragma unroll
  for (int n = 0; n < 2; ++n) {
    const int col = (wave * 2 + n) * 16 + lcol;
    const float b = bias[col];
#pragma unroll
    for (int mt = 0; mt < 4; ++mt)
#pragma unroll
      for (int rr = 0; rr < 4; ++rr) {
        const int row = mt * 16 + lr4 + rr;
        *reinterpret_cast<float*>(H + row * 528 + col * 4) = acc[mt][n][rr] + b;
      }
  }
}

// ---------------------------------------------------------------------------
// weight pack: f32 [K][128] -> bf16 MFMA B-fragment order (K zero-padded to 32n)
// ---------------------------------------------------------------------------
struct PackArgs {
  const float* src[15];
  int K[15];
  int base[16];
};

__global__ __launch_bounds__(256) void pack_w_kernel(PackArgs pa, bf16_t* __restrict__ dst) {
  const int id = blockIdx.x * 256 + threadIdx.x;  // < PW_TOTAL
  int m = 0;
#pragma unroll
  for (int i = 1; i < 15; ++i)
    if (id >= pa.base[i]) m = i;
  const int local = id - pa.base[m];
  const int kt = local >> 12;
  const int nt = (local >> 9) & 7;
  const int lane = (local >> 3) & 63;
  const int j = local & 7;
  const int k = kt * 32 + ((lane >> 4) << 3) + j;
  const int n = (nt << 4) + (lane & 15);
  float v = (k < pa.K[m]) ? pa.src[m][k * HDIM + n] : 0.f;
  dst[id] = (bf16_t)v;
}

// x f32 -> (bf16 copy, f32 master copy)
__global__ __launch_bounds__(256) void cvt_x_kernel(const float* __restrict__ x,
                                                    bf16_t* __restrict__ xb,
                                                    float* __restrict__ xc) {
  const int i = blockIdx.x * 256 + threadIdx.x;  // < 800000, 4 floats each
  f32x4 v = *reinterpret_cast<const f32x4*>(x + (size_t)i * 4);
  *reinterpret_cast<f32x4*>(xc + (size_t)i * 4) = v;
  v4bf h;
  h[0] = (bf16_t)v[0]; h[1] = (bf16_t)v[1]; h[2] = (bf16_t)v[2]; h[3] = (bf16_t)v[3];
  *reinterpret_cast<v4bf*>(xb + (size_t)i * 4) = h;
}

// ---------------------------------------------------------------------------
// edge embedding MLP: edge_attr[E,16] -> e[E,128] (bf16), LN, no residual
// LDS: A[64][80B] @0 ; h1 @0 (post-barrier) ; h2 @17408 ; h3 f32 @0
// ---------------------------------------------------------------------------
__global__ __launch_bounds__(256, 2) void emb_kernel(
    const float* __restrict__ eattr, const bf16_t* __restrict__ pw1,
    const bf16_t* __restrict__ pw2, const bf16_t* __restrict__ pw3,
    const float* __restrict__ b1, const float* __restrict__ b2, const float* __restrict__ b3,
    const float* __restrict__ g, const float* __restrict__ be, bf16_t* __restrict__ eb) {
  __shared__ char smem[34816];
  const int tid = threadIdx.x, lane = tid & 63, wave = tid >> 6;
  const int e0 = blockIdx.x * 64;
  {
    const int r = tid >> 2, q = tid & 3;
    f32x4 a = *reinterpret_cast<const f32x4*>(eattr + (size_t)(e0 + r) * 16 + q * 4);
    v4bf h;
    h[0] = (bf16_t)a[0]; h[1] = (bf16_t)a[1]; h[2] = (bf16_t)a[2]; h[3] = (bf16_t)a[3];
    *reinterpret_cast<v4bf*>(smem + r * 80 + q * 8) = h;
    v4bf z;
    z[0] = (bf16_t)0.f; z[1] = (bf16_t)0.f; z[2] = (bf16_t)0.f; z[3] = (bf16_t)0.f;
    *reinterpret_cast<v4bf*>(smem + r * 80 + 32 + q * 8) = z;  // zero-pad K 16..31
  }
  __syncthreads();
  f32x4 acc[4][2];
  zacc(acc);
  mfma_gemm<1, 80>(smem, pw1, acc, lane, wave);
  __syncthreads();
  store_h_bf16(smem, acc, b1, lane, wave, true);
  __syncthreads();
  zacc(acc);
  mfma_gemm<4, 272>(smem, pw2, acc, lane, wave);
  __syncthreads();
  store_h_bf16(smem + 17408, acc, b2, lane, wave, true);
  __syncthreads();
  zacc(acc);
  mfma_gemm<4, 272>(smem + 17408, pw3, acc, lane, wave);
  __syncthreads();
  store_h_f32(smem, acc, b3, lane, wave);
  __syncthreads();
  // LayerNorm + affine, write bf16 e
  const int r = tid >> 2, q = tid & 3;
  const char* hp = smem + r * 528 + q * 128;
  f32x4 v[8];
  float s = 0.f, s2 = 0.f;
#pragma unroll
  for (int i = 0; i < 8; ++i) {
    v[i] = *reinterpret_cast<const f32x4*>(hp + i * 16);
#pragma unroll
    for (int c = 0; c < 4; ++c) { s += v[i][c]; s2 += v[i][c] * v[i][c]; }
  }
  s += __shfl_xor(s, 1);  s += __shfl_xor(s, 2);
  s2 += __shfl_xor(s2, 1); s2 += __shfl_xor(s2, 2);
  const float mu = s * (1.f / 128.f);
  const float rs = rsqrtf(s2 * (1.f / 128.f) - mu * mu + 1e-5f);
  bf16_t* erow = eb + (size_t)(e0 + r) * HDIM;
#pragma unroll
  for (int i = 0; i < 8; ++i) {
    const int c0 = q * 32 + i * 4;
    f32x4 g4 = *reinterpret_cast<const f32x4*>(g + c0);
    f32x4 b4 = *reinterpret_cast<const f32x4*>(be + c0);
    v4bf o;
#pragma unroll
    for (int c = 0; c < 4; ++c) o[c] = (bf16_t)((v[i][c] - mu) * rs * g4[c] + b4[c]);
    *reinterpret_cast<v4bf*>(erow + c0) = o;
  }
}

// ---------------------------------------------------------------------------
// edge MLP: [x[dst] | x[src] | e] (3H) -> LN(...) + e ; fused atomic segment_sum
// LDS: A[64][784B] @0 ; h1 @0 (post-barrier) ; h2 @17408 ; h3 f32 @0
// ---------------------------------------------------------------------------
__global__ __launch_bounds__(256, 2) void edge_kernel(
    const int* __restrict__ eidx, const bf16_t* __restrict__ xb, bf16_t* __restrict__ eb,
    float* __restrict__ agg,
    const bf16_t* __restrict__ pw1, const bf16_t* __restrict__ pw2, const bf16_t* __restrict__ pw3,
    const float* __restrict__ b1, const float* __restrict__ b2, const float* __restrict__ b3,
    const float* __restrict__ g, const float* __restrict__ be, float* __restrict__ ef32out) {
  __shared__ char smem[50176];
  const int tid = threadIdx.x, lane = tid & 63, wave = tid >> 6;
  const int e0 = blockIdx.x * 64;
  {
    const int r = tid >> 2, q = tid & 3;
    const int edge = e0 + r;
    const int srcn = eidx[edge];        // edge_index[0] = src
    const int dstn = eidx[NE + edge];   // edge_index[1] = dst
    const bf16_t* xd = xb + (size_t)dstn * HDIM + q * 32;
    const bf16_t* xs = xb + (size_t)srcn * HDIM + q * 32;
    const bf16_t* ep = eb + (size_t)edge * HDIM + q * 32;
    char* arow = smem + r * 784 + q * 64;
#pragma unroll
    for (int i = 0; i < 4; ++i)
      *reinterpret_cast<u32x4*>(arow + i * 16) = *reinterpret_cast<const u32x4*>(xd + i * 8);
#pragma unroll
    for (int i = 0; i < 4; ++i)
      *reinterpret_cast<u32x4*>(arow + 256 + i * 16) = *reinterpret_cast<const u32x4*>(xs + i * 8);
#pragma unroll
    for (int i = 0; i < 4; ++i)
      *reinterpret_cast<u32x4*>(arow + 512 + i * 16) = *reinterpret_cast<const u32x4*>(ep + i * 8);
  }
  __syncthreads();
  f32x4 acc[4][2];
  zacc(acc);
  mfma_gemm<12, 784>(smem, pw1, acc, lane, wave);
  __syncthreads();
  store_h_bf16(smem, acc, b1, lane, wave, true);
  __syncthreads();
  zacc(acc);
  mfma_gemm<4, 272>(smem, pw2, acc, lane, wave);
  __syncthreads();
  store_h_bf16(smem + 17408, acc, b2, lane, wave, true);
  __syncthreads();
  zacc(acc);
  mfma_gemm<4, 272>(smem + 17408, pw3, acc, lane, wave);
  __syncthreads();
  store_h_f32(smem, acc, b3, lane, wave);
  __syncthreads();
  // LN + affine + residual(+e) + atomic segment_sum into agg[dst]
  const int r = tid >> 2, q = tid & 3;
  const int edge = e0 + r;
  const int dstn = eidx[NE + edge];
  const char* hp = smem + r * 528 + q * 128;
  f32x4 v[8];
  float s = 0.f, s2 = 0.f;
#pragma unroll
  for (int i = 0; i < 8; ++i) {
    v[i] = *reinterpret_cast<const f32x4*>(hp + i * 16);
#pragma unroll
    for (int c = 0; c < 4; ++c) { s += v[i][c]; s2 += v[i][c] * v[i][c]; }
  }
  s += __shfl_xor(s, 1);  s += __shfl_xor(s, 2);
  s2 += __shfl_xor(s2, 1); s2 += __shfl_xor(s2, 2);
  const float mu = s * (1.f / 128.f);
  const float rs = rsqrtf(s2 * (1.f / 128.f) - mu * mu + 1e-5f);
  float* aggrow = agg + (size_t)dstn * HDIM;
  bf16_t* erow = eb + (size_t)edge * HDIM;
#pragma unroll
  for (int i = 0; i < 8; ++i) {
    const int c0 = q * 32 + i * 4;
    f32x4 g4 = *reinterpret_cast<const f32x4*>(g + c0);
    f32x4 b4 = *reinterpret_cast<const f32x4*>(be + c0);
    f32x4 o;
#pragma unroll
    for (int c = 0; c < 4; ++c) {
      const float eo = (float)erow[c0 + c];
      o[c] = (v[i][c] - mu) * rs * g4[c] + b4[c] + eo;
      atomicAdd(aggrow + c0 + c, o[c]);
    }
    if (ef32out) {  // last block: f32 straight to d_out e-region
      *reinterpret_cast<f32x4*>(ef32out + (size_t)edge * HDIM + c0) = o;
    } else {
      v4bf ob;
      ob[0] = (bf16_t)o[0]; ob[1] = (bf16_t)o[1]; ob[2] = (bf16_t)o[2]; ob[3] = (bf16_t)o[3];
      *reinterpret_cast<v4bf*>(erow + c0) = ob;  // in-place: own rows only
    }
  }
}

// ---------------------------------------------------------------------------
// node MLP: [x | agg] (2H) -> LN(...) + x
// LDS: A[64][528B] @0 ; h1 @0 (post-barrier) ; h2 @17408 ; h3 f32 @0
// ---------------------------------------------------------------------------
__global__ __launch_bounds__(256, 2) void node_kernel(
    const bf16_t* __restrict__ xb, const float* __restrict__ agg, const float* __restrict__ xc,
    const bf16_t* __restrict__ pw1, const bf16_t* __restrict__ pw2, const bf16_t* __restrict__ pw3,
    const float* __restrict__ b1, const float* __restrict__ b2, const float* __restrict__ b3,
    const float* __restrict__ g, const float* __restrict__ be,
    float* __restrict__ xout, bf16_t* __restrict__ xbout) {
  __shared__ char smem[34816];
  const int tid = threadIdx.x, lane = tid & 63, wave = tid >> 6;
  const int n0 = blockIdx.x * 64;
  {
    const int r = tid >> 2, q = tid & 3;
    int node = n0 + r;
    if (node >= NN) node = NN - 1;  // tail: clamp gather, skip store later
    const bf16_t* xp = xb + (size_t)node * HDIM + q * 32;
    char* arow = smem + r * 528 + q * 64;
#pragma unroll
    for (int i = 0; i < 4; ++i)
      *reinterpret_cast<u32x4*>(arow + i * 16) = *reinterpret_cast<const u32x4*>(xp + i * 8);
    const float* ap = agg + (size_t)node * HDIM + q * 32;
#pragma unroll
    for (int i = 0; i < 4; ++i) {
      f32x4 u = *reinterpret_cast<const f32x4*>(ap + i * 8);
      f32x4 w = *reinterpret_cast<const f32x4*>(ap + i * 8 + 4);
      v8bf h;
      h[0] = (bf16_t)u[0]; h[1] = (bf16_t)u[1]; h[2] = (bf16_t)u[2]; h[3] = (bf16_t)u[3];
      h[4] = (bf16_t)w[0]; h[5] = (bf16_t)w[1]; h[6] = (bf16_t)w[2]; h[7] = (bf16_t)w[3];
      *reinterpret_cast<v8bf*>(arow + 256 + i * 16) = h;
    }
  }
  __syncthreads();
  f32x4 acc[4][2];
  zacc(acc);
  mfma_gemm<8, 528>(smem, pw1, acc, lane, wave);
  __syncthreads();
  store_h_bf16(smem, acc, b1, lane, wave, true);
  __syncthreads();
  zacc(acc);
  mfma_gemm<4, 272>(smem, pw2, acc, lane, wave);
  __syncthreads();
  store_h_bf16(smem + 17408, acc, b2, lane, wave, true);
  __syncthreads();
  zacc(acc);
  mfma_gemm<4, 272>(smem + 17408, pw3, acc, lane, wave);
  __syncthreads();
  store_h_f32(smem, acc, b3, lane, wave);
  __syncthreads();
  const int r = tid >> 2, q = tid & 3;
  const int node = n0 + r;
  if (node < NN) {
    const char* hp = smem + r * 528 + q * 128;
    f32x4 v[8];
    float s = 0.f, s2 = 0.f;
#pragma unroll
    for (int i = 0; i < 8; ++i) {
      v[i] = *reinterpret_cast<const f32x4*>(hp + i * 16);
#pragma unroll
      for (int c = 0; c < 4; ++c) { s += v[i][c]; s2 += v[i][c] * v[i][c]; }
    }
    s += __shfl_xor(s, 1);  s += __shfl_xor(s, 2);
    s2 += __shfl_xor(s2, 1); s2 += __shfl_xor(s2, 2);
    const float mu = s * (1.f / 128.f);
    const float rs = rsqrtf(s2 * (1.f / 128.f) - mu * mu + 1e-5f);
    const float* xrow = xc + (size_t)node * HDIM;
#pragma unroll
    for (int i = 0; i < 8; ++i) {
      const int c0 = q * 32 + i * 4;
      f32x4 g4 = *reinterpret_cast<const f32x4*>(g + c0);
      f32x4 b4 = *reinterpret_cast<const f32x4*>(be + c0);
      f32x4 xo = *reinterpret_cast<const f32x4*>(xrow + c0);
      f32x4 o;
#pragma unroll
      for (int c = 0; c < 4; ++c) o[c] = (v[i][c] - mu) * rs * g4[c] + b4[c] + xo[c];
      *reinterpret_cast<f32x4*>(xout + (size_t)node * HDIM + c0) = o;
      if (xbout) {
        v4bf ob;
        ob[0] = (bf16_t)o[0]; ob[1] = (bf16_t)o[1]; ob[2] = (bf16_t)o[2]; ob[3] = (bf16_t)o[3];
        *reinterpret_cast<v4bf*>(xbout + (size_t)node * HDIM + c0) = ob;
      }
    }
  }
}

// ---------------------------------------------------------------------------
extern "C" void kernel_launch(void* const* d_in, const int* in_sizes, int n_in,
                              void* d_out, int out_size, void* d_ws, size_t ws_size,
                              hipStream_t stream) {
  (void)in_sizes; (void)n_in; (void)out_size; (void)ws_size;
  const float* x       = (const float*)d_in[0];
  const int*   eidx    = (const int*)d_in[1];
  const float* eattr   = (const float*)d_in[2];
  const float* emb_W1  = (const float*)d_in[3];
  const float* emb_b1  = (const float*)d_in[4];
  const float* emb_W2  = (const float*)d_in[5];
  const float* emb_b2  = (const float*)d_in[6];
  const float* emb_W3  = (const float*)d_in[7];
  const float* emb_b3  = (const float*)d_in[8];
  const float* emb_g   = (const float*)d_in[9];
  const float* emb_be  = (const float*)d_in[10];
  const float* edge_W1 = (const float*)d_in[11];
  const float* edge_b1 = (const float*)d_in[12];
  const float* edge_W2 = (const float*)d_in[13];
  const float* edge_b2 = (const float*)d_in[14];
  const float* edge_W3 = (const float*)d_in[15];
  const float* edge_b3 = (const float*)d_in[16];
  const float* edge_g  = (const float*)d_in[17];
  const float* edge_be = (const float*)d_in[18];
  const float* node_W1 = (const float*)d_in[19];
  const float* node_b1 = (const float*)d_in[20];
  const float* node_W2 = (const float*)d_in[21];
  const float* node_b2 = (const float*)d_in[22];
  const float* node_W3 = (const float*)d_in[23];
  const float* node_b3 = (const float*)d_in[24];
  const float* node_g  = (const float*)d_in[25];
  const float* node_be = (const float*)d_in[26];

  char* ws = (char*)d_ws;
  bf16_t* pw  = (bf16_t*)(ws + WS_PW);
  bf16_t* xb  = (bf16_t*)(ws + WS_XB);
  float*  xc  = (float*)(ws + WS_XC);
  float*  agg = (float*)(ws + WS_AGG);
  bf16_t* eb  = (bf16_t*)(ws + WS_EB);
  float* xout_final = (float*)d_out;              // [25000*128]
  float* eout_final = (float*)d_out + 3200000;    // [400000*128]

  PackArgs pa;
  const float* srcs[15] = {
      emb_W1, emb_W2, emb_W3,
      edge_W1, edge_W2, edge_W3,
      edge_W1 + 49152, edge_W2 + 16384, edge_W3 + 16384,
      node_W1, node_W2, node_W3,
      node_W1 + 32768, node_W2 + 16384, node_W3 + 16384};
  const int Ks[15]    = {16, 128, 128, 384, 128, 128, 384, 128, 128, 256, 128, 128, 256, 128, 128};
  const int bases[16] = {0, 4096, 20480, 36864, 86016, 102400, 118784, 167936, 184320,
                         200704, 233472, 249856, 266240, 299008, 315392, PW_TOTAL};
  for (int i = 0; i < 15; ++i) { pa.src[i] = srcs[i]; pa.K[i] = Ks[i]; }
  for (int i = 0; i < 16; ++i) pa.base[i] = bases[i];

  pack_w_kernel<<<PW_TOTAL / 256, 256, 0, stream>>>(pa, pw);
  cvt_x_kernel<<<3125, 256, 0, stream>>>(x, xb, xc);
  emb_kernel<<<NE / 64, 256, 0, stream>>>(eattr, pw + PW_EMB1, pw + PW_EMB2, pw + PW_EMB3,
                                          emb_b1, emb_b2, emb_b3, emb_g, emb_be, eb);
  for (int l = 0; l < 2; ++l) {
    hipMemsetAsync(agg, 0, (size_t)NN * HDIM * 4, stream);
    const bf16_t* pe1 = pw + PW_EDGE1 + l * 81920;
    edge_kernel<<<NE / 64, 256, 0, stream>>>(
        eidx, xb, eb, agg, pe1, pe1 + 49152, pe1 + 65536,
        edge_b1 + l * HDIM, edge_b2 + l * HDIM, edge_b3 + l * HDIM,
        edge_g + l * HDIM, edge_be + l * HDIM,
        (l == 1) ? eout_final : nullptr);
    const bf16_t* pn1 = pw + PW_NODE1 + l * 65536;
    node_kernel<<<(NN + 63) / 64, 256, 0, stream>>>(
        xb, agg, xc, pn1, pn1 + 32768, pn1 + 49152,
        node_b1 + l * HDIM, node_b2 + l * HDIM, node_b3 + l * HDIM,
        node_g + l * HDIM, node_be + l * HDIM,
        (l == 1) ? xout_final : xc, (l == 0) ? xb : nullptr);
  }
}